// Round 1
// baseline (2961.726 us; speedup 1.0000x reference)
//
#include <hip/hip_runtime.h>
#include <hip/hip_bf16.h>

// Seq2Seq (batch=1): enc LSTM (S=256) -> dec LSTM (T=256, teacher forcing)
// -> linear (VOUT=32000) -> log_softmax.
// Structure:
//   1) input_gemm: gates_x[t][r] = dot(emb[tok(t)], Wih[r]) + bih[r] + bhh[r]
//      (MFMA bf16, f32->bf16 cvt in-register)      [enc + dec, parallel work]
//   2) 512x lstm_step kernels (sequential): gates = gates_x + Whh@h; c,h update
//   3) out_gemm: logits = Hs @ lin_W^T + b (MFMA bf16)
//   4) log_softmax per row
//
// v1 = correctness-first: per-step kernel launches for the recurrence.

#define HDIM 1024
#define SLEN 256
#define TLEN 256
#define VOUTN 32000
#define G4 4096

typedef __bf16 bf16_t;
typedef __bf16 bf16x8 __attribute__((ext_vector_type(8)));
typedef float f32x4 __attribute__((ext_vector_type(4)));

static __device__ inline bf16x8 cvt8(float4 a, float4 b) {
    bf16x8 r;
    r[0] = (__bf16)a.x; r[1] = (__bf16)a.y; r[2] = (__bf16)a.z; r[3] = (__bf16)a.w;
    r[4] = (__bf16)b.x; r[5] = (__bf16)b.y; r[6] = (__bf16)b.z; r[7] = (__bf16)b.w;
    return r;
}

// C[t][n] = dot(emb[tok(t)], W[n]) + bih[n] + bhh[n]
// grid 64 blocks x 256 thr; wave handles one 16-wide n-tile, loops all 16 m-tiles.
__global__ __launch_bounds__(256) void input_gemm(
    const float* __restrict__ emb,   // [V, 1024]
    const int* __restrict__ toks,    // [256]
    const int* __restrict__ start,   // null => tok(t)=toks[t]; else shifted decoder input
    const float* __restrict__ W,     // [4096, 1024]
    const float* __restrict__ bih,   // [4096]
    const float* __restrict__ bhh,   // [4096]
    float* __restrict__ out)         // [256, 4096]
{
    __shared__ int stok[SLEN];
    int tid = threadIdx.x;
    {
        int t = tid;
        int tok;
        if (start) tok = (t == 0) ? start[0] : toks[t - 1];
        else       tok = toks[t];
        stok[t] = tok;
    }
    __syncthreads();

    int wave = tid >> 6, lane = tid & 63;
    int l15 = lane & 15, quad = lane >> 4;
    int n = (blockIdx.x * 4 + wave) * 16 + l15;
    const float* wrow = W + (size_t)n * HDIM + quad * 8;

    f32x4 acc[16] = {};
    for (int kt = 0; kt < HDIM / 32; ++kt) {
        float4 b0 = *(const float4*)(wrow + kt * 32);
        float4 b1 = *(const float4*)(wrow + kt * 32 + 4);
        bf16x8 bf = cvt8(b0, b1);
#pragma unroll
        for (int mt = 0; mt < 16; ++mt) {
            const float* arow = emb + (size_t)stok[mt * 16 + l15] * HDIM + kt * 32 + quad * 8;
            bf16x8 af = cvt8(*(const float4*)arow, *(const float4*)(arow + 4));
            acc[mt] = __builtin_amdgcn_mfma_f32_16x16x32_bf16(af, bf, acc[mt], 0, 0, 0);
        }
    }
    float bias = bih[n] + bhh[n];
#pragma unroll
    for (int mt = 0; mt < 16; ++mt)
#pragma unroll
        for (int r = 0; r < 4; ++r) {
            int t = mt * 16 + quad * 4 + r;
            out[(size_t)t * G4 + n] = acc[mt][r] + bias;
        }
}

// One LSTM step. grid 256 blocks x 256 thr. Block b owns hidden slice j0=b*4..b*4+3
// (rows {j, j+1024, j+2048, j+3072}); c is block-owned (in-place safe), h double-buffered.
__global__ __launch_bounds__(256) void lstm_step(
    const float* __restrict__ xw,     // [4096] precomputed x@Wih^T + bih + bhh for this t
    const float* __restrict__ Whh,    // [4096, 1024]
    const float* __restrict__ h_in,   // [1024]
    float* __restrict__ h_out,        // [1024]
    float* __restrict__ c,            // [1024]
    bf16_t* __restrict__ h_save)      // nullable: Hs row (bf16)
{
    __shared__ float sh[HDIM];
    __shared__ float sg[16];
    int tid = threadIdx.x;
    ((float4*)sh)[tid] = ((const float4*)h_in)[tid];  // stage h (4 KB)
    __syncthreads();

    int grp = tid >> 4;      // 16 groups = 16 rows
    int l = tid & 15;
    int q = grp >> 2;        // gate 0..3 (i,f,g,o)
    int jl = grp & 3;        // local hidden idx
    int j0 = blockIdx.x * 4;
    int row = q * HDIM + j0 + jl;
    const float4* w = (const float4*)(Whh + (size_t)row * HDIM);
    const float4* hv4 = (const float4*)sh;

    float sum = 0.f;
#pragma unroll
    for (int i = 0; i < 16; ++i) {
        float4 wv = w[l * 4 + i];          // wait: need coalesced across l
        float4 hv = hv4[l * 4 + i];
        sum += wv.x * hv.x + wv.y * hv.y + wv.z * hv.z + wv.w * hv.w;
    }
    // NOTE: pattern above gives lane l the contiguous chunk [l*16, l*16+64) bytes
    // repeated 16x? -- fixed below: use stride-16 float4 indexing instead.
    // (kept simple & correct: lane l reads float4 index l + 16*i)
    sum = 0.f;
#pragma unroll
    for (int i = 0; i < 16; ++i) {
        float4 wv = w[l + 16 * i];
        float4 hv = hv4[l + 16 * i];
        sum += wv.x * hv.x + wv.y * hv.y + wv.z * hv.z + wv.w * hv.w;
    }
    sum += __shfl_down(sum, 8, 16);
    sum += __shfl_down(sum, 4, 16);
    sum += __shfl_down(sum, 2, 16);
    sum += __shfl_down(sum, 1, 16);
    if (l == 0) sg[grp] = sum;
    __syncthreads();

    if (tid < 4) {
        int j = j0 + tid;
        float gi = sg[0 * 4 + tid] + xw[0 * HDIM + j];
        float gf = sg[1 * 4 + tid] + xw[1 * HDIM + j];
        float gg = sg[2 * 4 + tid] + xw[2 * HDIM + j];
        float go = sg[3 * 4 + tid] + xw[3 * HDIM + j];
        float ii = 1.f / (1.f + expf(-gi));
        float ff = 1.f / (1.f + expf(-gf));
        float g  = tanhf(gg);
        float oo = 1.f / (1.f + expf(-go));
        float cn = ff * c[j] + ii * g;
        float hn = oo * tanhf(cn);
        c[j] = cn;
        h_out[j] = hn;
        if (h_save) h_save[j] = (bf16_t)hn;
    }
}

// logits[t][n] = dot(Hs_bf16[t], lin_W[n]) + b[n]
// grid 500 blocks x 256 thr; wave per 16-wide n-tile, loops 16 m-tiles.
__global__ __launch_bounds__(256) void out_gemm(
    const bf16_t* __restrict__ Hs,   // [256, 1024] bf16
    const float* __restrict__ W,     // [32000, 1024]
    const float* __restrict__ bias,  // [32000]
    float* __restrict__ out)         // [256, 32000]
{
    int tid = threadIdx.x;
    int wave = tid >> 6, lane = tid & 63;
    int l15 = lane & 15, quad = lane >> 4;
    int n = (blockIdx.x * 4 + wave) * 16 + l15;
    const float* wrow = W + (size_t)n * HDIM + quad * 8;

    f32x4 acc[16] = {};
    for (int kt = 0; kt < HDIM / 32; ++kt) {
        float4 b0 = *(const float4*)(wrow + kt * 32);
        float4 b1 = *(const float4*)(wrow + kt * 32 + 4);
        bf16x8 bf = cvt8(b0, b1);
#pragma unroll
        for (int mt = 0; mt < 16; ++mt) {
            bf16x8 af = *(const bf16x8*)(Hs + (size_t)(mt * 16 + l15) * HDIM + kt * 32 + quad * 8);
            acc[mt] = __builtin_amdgcn_mfma_f32_16x16x32_bf16(af, bf, acc[mt], 0, 0, 0);
        }
    }
    float bv = bias[n];
#pragma unroll
    for (int mt = 0; mt < 16; ++mt)
#pragma unroll
        for (int r = 0; r < 4; ++r) {
            int t = mt * 16 + quad * 4 + r;
            out[(size_t)t * VOUTN + n] = acc[mt][r] + bv;
        }
}

// in-place log_softmax per row; 256 blocks (one per t) x 256 thr
__global__ __launch_bounds__(256) void log_softmax_k(float* __restrict__ out)
{
    float* row = out + (size_t)blockIdx.x * VOUTN;
    int tid = threadIdx.x;
    int wave = tid >> 6, lane = tid & 63;
    __shared__ float sm[4], ss[4];

    float m = -1e30f;
    for (int i = tid; i < VOUTN; i += 256) m = fmaxf(m, row[i]);
    for (int o = 32; o; o >>= 1) m = fmaxf(m, __shfl_down(m, o, 64));
    if (lane == 0) sm[wave] = m;
    __syncthreads();
    float bm = fmaxf(fmaxf(sm[0], sm[1]), fmaxf(sm[2], sm[3]));

    float s = 0.f;
    for (int i = tid; i < VOUTN; i += 256) s += expf(row[i] - bm);
    for (int o = 32; o; o >>= 1) s += __shfl_down(s, o, 64);
    if (lane == 0) ss[wave] = s;
    __syncthreads();
    float lse = bm + logf(ss[0] + ss[1] + ss[2] + ss[3]);

    for (int i = tid; i < VOUTN; i += 256) row[i] -= lse;
}

extern "C" void kernel_launch(void* const* d_in, const int* in_sizes, int n_in,
                              void* d_out, int out_size, void* d_ws, size_t ws_size,
                              hipStream_t stream) {
    const int*   src     = (const int*)d_in[0];
    const int*   trg     = (const int*)d_in[1];
    const int*   start   = (const int*)d_in[2];
    const float* enc_emb = (const float*)d_in[3];
    const float* enc_Wih = (const float*)d_in[4];
    const float* enc_Whh = (const float*)d_in[5];
    const float* enc_bih = (const float*)d_in[6];
    const float* enc_bhh = (const float*)d_in[7];
    const float* dec_emb = (const float*)d_in[8];
    const float* dec_Wih = (const float*)d_in[9];
    const float* dec_Whh = (const float*)d_in[10];
    const float* dec_bih = (const float*)d_in[11];
    const float* dec_bhh = (const float*)d_in[12];
    const float* lin_W   = (const float*)d_in[13];
    const float* lin_b   = (const float*)d_in[14];
    float* out = (float*)d_out;

    char* ws = (char*)d_ws;
    float*  encXW = (float*)(ws);                          // 256*4096 f32 = 4 MiB
    float*  decXW = (float*)(ws + 4194304);                // 4 MiB
    bf16_t* Hs    = (bf16_t*)(ws + 8388608);               // 256*1024 bf16 = 512 KiB
    float*  hbuf  = (float*)(ws + 8912896);                // 2*1024 f32
    float*  cbuf  = (float*)(ws + 8921088);                // 1024 f32

    // zero h0/c0 (ws is poisoned 0xAA before every launch)
    hipMemsetAsync(hbuf, 0, (2 * HDIM + HDIM) * sizeof(float), stream);

    // precompute x@Wih^T + biases for all timesteps (parallel across t)
    input_gemm<<<64, 256, 0, stream>>>(enc_emb, src, nullptr, enc_Wih, enc_bih, enc_bhh, encXW);
    input_gemm<<<64, 256, 0, stream>>>(dec_emb, trg, start,   dec_Wih, dec_bih, dec_bhh, decXW);

    // encoder recurrence
    for (int t = 0; t < SLEN; ++t) {
        lstm_step<<<256, 256, 0, stream>>>(encXW + (size_t)t * G4, enc_Whh,
                                           hbuf + (t & 1) * HDIM,
                                           hbuf + ((t + 1) & 1) * HDIM,
                                           cbuf, nullptr);
    }
    // decoder recurrence (continues h/c), saving h_t in bf16 for the output GEMM
    for (int t = 0; t < TLEN; ++t) {
        int s = SLEN + t;
        lstm_step<<<256, 256, 0, stream>>>(decXW + (size_t)t * G4, dec_Whh,
                                           hbuf + (s & 1) * HDIM,
                                           hbuf + ((s + 1) & 1) * HDIM,
                                           cbuf, Hs + (size_t)t * HDIM);
    }

    // output projection + log_softmax
    out_gemm<<<500, 256, 0, stream>>>(Hs, lin_W, lin_b, out);
    log_softmax_k<<<256, 256, 0, stream>>>(out);
}